// Round 10
// baseline (90.225 us; speedup 1.0000x reference)
//
#include <hip/hip_runtime.h>

#define B 2
#define N 16384
#define NPOINT 4096
#define C 64
#define NSAMPLE 32

#define NCELL 1000        // 10x10x10 grid, cell size 0.1 == radius
#define OFF_STRIDE 1056   // offsets stride per batch (1001 used)
#define CAP 192           // per-query candidate capacity (mean ~69)

#define NTILE_BLOCKS (B * (N / 256))   // 128 transpose blocks (4 sub-tiles each)

// Threshold exactly as the JAX/numpy reference sees it:
// float32(double(0.1)*double(0.1)) = 0.009999999776482582f
__device__ __forceinline__ float r2_thresh() { return (float)(0.1 * 0.1); }

__device__ __forceinline__ int clamp09(int v) { return v < 0 ? 0 : (v > 9 ? 9 : v); }

__device__ __forceinline__ int cell_of(float x, float y, float z) {
    const int ix = clamp09((int)floorf(x * 10.0f));
    const int iy = clamp09((int)floorf(y * 10.0f));
    const int iz = clamp09((int)floorf(z * 10.0f));
    return (ix * 10 + iy) * 10 + iz;
}

// Exclusive scan of cnts[1024] -> cursors in cur[1024]; optionally write off[0..1000].
__device__ __forceinline__ void scan_and_cursor(int* cnts, int* cur, int t,
                                                int* off_global) {
    const int v = cnts[t];
    cur[t] = v;
    __syncthreads();
#pragma unroll
    for (int d = 1; d < 1024; d <<= 1) {
        const int add = (t >= d) ? cur[t - d] : 0;
        __syncthreads();
        cur[t] += add;
        __syncthreads();
    }
    const int excl = cur[t] - v;
    if (off_global && t <= NCELL) off_global[t] = excl;
    __syncthreads();
    cur[t] = excl;
    __syncthreads();
}

// ---------------- Kernel P: transpose (blocks 0..127) + grid build (blocks 128..129) ----------------
__global__ void __launch_bounds__(1024) prep_kernel(
    const float* __restrict__ feat,     // (B, C, N)
    const float* __restrict__ xyz,      // (B, N, 3)
    const float* __restrict__ new_xyz,  // (B, NPOINT, 3)
    float* __restrict__ ft,             // (B, N, C)
    float4* __restrict__ binned,        // (B, N) {x,y,z,idx}
    int* __restrict__ off,              // (B, OFF_STRIDE)
    int* __restrict__ qperm)            // (B, NPOINT)
{
    __shared__ float tile[64 * 65];
    __shared__ int cnts[1024];
    __shared__ int cur[1024];

    const int t = threadIdx.x;

    if (blockIdx.x < NTILE_BLOCKS) {
        // ---- transpose branch: 4 sub-tiles of 64n x 64c ----
        const int tb = blockIdx.x;
        const int b = tb / (N / 256);
        const int n0b = (tb % (N / 256)) * 256;
        const int l = t & 63;
        const int w = t >> 6;   // 0..15
        for (int si = 0; si < 4; ++si) {
            const int n0 = n0b + si * 64;
#pragma unroll
            for (int it = 0; it < 4; ++it) {
                const int c = it * 16 + w;
                tile[c * 65 + l] = feat[((size_t)b * C + c) * N + n0 + l];
            }
            __syncthreads();
#pragma unroll
            for (int it = 0; it < 4; ++it) {
                const int nn = it * 16 + w;
                ft[((size_t)b * N + n0 + nn) * C + l] = tile[l * 65 + nn];
            }
            __syncthreads();
        }
        return;
    }

    // ---- build branch: one block per batch, all counters in LDS ----
    const int b = blockIdx.x - NTILE_BLOCKS;

    // points: histogram
    cnts[t] = 0;
    __syncthreads();
    for (int i = t; i < N; i += 1024) {
        const float x = xyz[((size_t)b * N + i) * 3 + 0];
        const float y = xyz[((size_t)b * N + i) * 3 + 1];
        const float z = xyz[((size_t)b * N + i) * 3 + 2];
        atomicAdd(&cnts[cell_of(x, y, z)], 1);
    }
    __syncthreads();
    scan_and_cursor(cnts, cur, t, off + b * OFF_STRIDE);
    // points: scatter
    for (int i = t; i < N; i += 1024) {
        const float x = xyz[((size_t)b * N + i) * 3 + 0];
        const float y = xyz[((size_t)b * N + i) * 3 + 1];
        const float z = xyz[((size_t)b * N + i) * 3 + 2];
        const int pos = atomicAdd(&cur[cell_of(x, y, z)], 1);
        float4 v;
        v.x = x; v.y = y; v.z = z; v.w = __int_as_float(i);
        binned[(size_t)b * N + pos] = v;
    }
    __syncthreads();

    // queries: histogram
    cnts[t] = 0;
    __syncthreads();
    for (int i = t; i < NPOINT; i += 1024) {
        const float x = new_xyz[((size_t)b * NPOINT + i) * 3 + 0];
        const float y = new_xyz[((size_t)b * NPOINT + i) * 3 + 1];
        const float z = new_xyz[((size_t)b * NPOINT + i) * 3 + 2];
        atomicAdd(&cnts[cell_of(x, y, z)], 1);
    }
    __syncthreads();
    scan_and_cursor(cnts, cur, t, nullptr);
    // queries: scatter -> qperm
    for (int i = t; i < NPOINT; i += 1024) {
        const float x = new_xyz[((size_t)b * NPOINT + i) * 3 + 0];
        const float y = new_xyz[((size_t)b * NPOINT + i) * 3 + 1];
        const float z = new_xyz[((size_t)b * NPOINT + i) * 3 + 2];
        const int pos = atomicAdd(&cur[cell_of(x, y, z)], 1);
        qperm[b * NPOINT + pos] = i;
    }
}

// ---------------- exact linear-scan fallback (in-wave) ----------------
__device__ void linear_ball_fallback(const float* __restrict__ xb,
                                     float cx, float cy, float cz,
                                     int lane, unsigned long long lanemask_lt,
                                     int* out) {
    const float r2 = r2_thresh();
    int cnt = 0, first_idx = 0;
    for (int base = 0; base < N; base += 64) {
        const int i = base + lane;
        const float x = xb[i * 3 + 0];
        const float y = xb[i * 3 + 1];
        const float z = xb[i * 3 + 2];
        float d2;
        {
#pragma clang fp contract(off)
            float dx = x - cx;
            float dy = y - cy;
            float dz = z - cz;
            d2 = dx * dx + dy * dy + dz * dz;
        }
        const bool in = d2 < r2;
        const unsigned long long m = __ballot(in);
        if (in) {
            const int pos = cnt + __popcll(m & lanemask_lt);
            if (pos < NSAMPLE) out[pos] = i;
        }
        if (cnt == 0 && m != 0ull) first_idx = base + __builtin_ctzll(m);
        cnt += __popcll(m);
        if (cnt >= NSAMPLE) break;
    }
    if (cnt < NSAMPLE) {
        if (cnt == 0) first_idx = 0;
        for (int pos = cnt + lane; pos < NSAMPLE; pos += 64) out[pos] = first_idx;
    }
}

// Rank-select the NSAMPLE smallest indices from cand[0..K) (K <= CAP) -> out.
__device__ __forceinline__ void rank_select(const int* cand, int K, int lane,
                                            int* __restrict__ out) {
    const int e0 = (lane < K) ? cand[lane] : 0x7FFFFFFF;
    const int e1 = (64 + lane < K) ? cand[64 + lane] : 0x7FFFFFFF;
    const int e2 = (128 + lane < K) ? cand[128 + lane] : 0x7FFFFFFF;
    int r0 = 0, r1 = 0, r2i = 0;
    if (K <= 64) {
        for (int k = 0; k < K; ++k) { const int v = cand[k]; r0 += (v < e0); }
    } else if (K <= 128) {
        for (int k = 0; k < K; ++k) { const int v = cand[k]; r0 += (v < e0); r1 += (v < e1); }
    } else {
        for (int k = 0; k < K; ++k) {
            const int v = cand[k];
            r0 += (v < e0); r1 += (v < e1); r2i += (v < e2);
        }
    }
    if (lane < K && r0 < NSAMPLE) out[r0] = e0;
    if (64 + lane < K && r1 < NSAMPLE) out[r1] = e1;
    if (128 + lane < K && r2i < NSAMPLE) out[r2i] = e2;

    if (K < NSAMPLE) {
        int mn = min(e0, min(e1, e2));
#pragma unroll
        for (int d = 32; d; d >>= 1) mn = min(mn, __shfl_xor(mn, d));
        const int fill = (K > 0) ? mn : 0;
        for (int pos = K + lane; pos < NSAMPLE; pos += 64) out[pos] = fill;
    }
}

// ---------------- Kernel 1g: ball query via grid, TWO sorted queries per wave ----------------
// Adjacent sorted queries share their cell neighborhood: each 64-point chunk is
// loaded once and distance-tested against both centers (loads amortized 2x).
__global__ void __launch_bounds__(256) ball_query_pair_kernel(
    const float4* __restrict__ binned,   // (B, N) {x,y,z,idx}
    const int* __restrict__ off,         // (B, OFF_STRIDE)
    const float* __restrict__ new_xyz,   // (B, NPOINT, 3)
    const float* __restrict__ xyz,       // (B, N, 3) overflow fallback
    const int* __restrict__ qperm,       // (B, NPOINT)
    int* __restrict__ idx_out)           // (B, NPOINT, NSAMPLE)
{
    __shared__ int cand_s[8][CAP];      // 4 waves x 2 queries
    const int lane = threadIdx.x & 63;
    const int wib = threadIdx.x >> 6;

    const int nwg = B * NPOINT / 8;                 // 1024 blocks, % 8 == 0
    const int g = blockIdx.x;
    const int swz = (g & 7) * (nwg / 8) + (g >> 3); // bijective XCD swizzle
    const int gw = swz * 4 + wib;                   // wave id over 4096
    const int b = gw / (NPOINT / 2);
    const int r = gw % (NPOINT / 2);

    const int j0 = qperm[b * NPOINT + 2 * r + 0];   // broadcast loads
    const int j1 = qperm[b * NPOINT + 2 * r + 1];

    const float c0x = new_xyz[((size_t)b * NPOINT + j0) * 3 + 0];
    const float c0y = new_xyz[((size_t)b * NPOINT + j0) * 3 + 1];
    const float c0z = new_xyz[((size_t)b * NPOINT + j0) * 3 + 2];
    const float c1x = new_xyz[((size_t)b * NPOINT + j1) * 3 + 0];
    const float c1y = new_xyz[((size_t)b * NPOINT + j1) * 3 + 1];
    const float c1z = new_xyz[((size_t)b * NPOINT + j1) * 3 + 2];

    int* cand0 = cand_s[wib * 2 + 0];
    int* cand1 = cand_s[wib * 2 + 1];
    const float4* __restrict__ bb = binned + (size_t)b * N;
    const int* __restrict__ ob = off + b * OFF_STRIDE;
    int* __restrict__ out0 = idx_out + ((size_t)b * NPOINT + j0) * NSAMPLE;
    int* __restrict__ out1 = idx_out + ((size_t)b * NPOINT + j1) * NSAMPLE;

    const float r2 = r2_thresh();
    const unsigned long long lanemask_lt = (lane == 63) ? 0x7FFFFFFFFFFFFFFFull
                                                        : ((1ull << lane) - 1ull);

    // Per-axis UNION of the two query windows (each ball's cells are inside
    // its own window, so the union covers both; distance test filters).
    const int lox = max(0, min((int)floorf((c0x - 0.1001f) * 10.0f),
                               (int)floorf((c1x - 0.1001f) * 10.0f)));
    const int hix = min(9, max((int)floorf((c0x + 0.1001f) * 10.0f),
                               (int)floorf((c1x + 0.1001f) * 10.0f)));
    const int loy = max(0, min((int)floorf((c0y - 0.1001f) * 10.0f),
                               (int)floorf((c1y - 0.1001f) * 10.0f)));
    const int hiy = min(9, max((int)floorf((c0y + 0.1001f) * 10.0f),
                               (int)floorf((c1y + 0.1001f) * 10.0f)));
    const int loz = max(0, min((int)floorf((c0z - 0.1001f) * 10.0f),
                               (int)floorf((c1z - 0.1001f) * 10.0f)));
    const int hiz = min(9, max((int)floorf((c0z + 0.1001f) * 10.0f),
                               (int)floorf((c1z + 0.1001f) * 10.0f)));

    int K0 = 0, K1 = 0;
    for (int ix = lox; ix <= hix; ++ix) {
        for (int iy = loy; iy <= hiy; ++iy) {
            const int rowc = (ix * 10 + iy) * 10;
            const int s0 = ob[rowc + loz];
            const int s1 = ob[rowc + hiz + 1];  // z cells contiguous -> one segment
            for (int curp = s0; curp < s1; curp += 64) {
                const int i = curp + lane;
                const bool valid = (i < s1);
                float4 pv;
                if (valid) pv = bb[i];
                else { pv.x = 1e9f; pv.y = 1e9f; pv.z = 1e9f; pv.w = 0.0f; }
                float d20, d21;
                {
#pragma clang fp contract(off)
                    float dx0 = pv.x - c0x, dy0 = pv.y - c0y, dz0 = pv.z - c0z;
                    d20 = dx0 * dx0 + dy0 * dy0 + dz0 * dz0;
                    float dx1 = pv.x - c1x, dy1 = pv.y - c1y, dz1 = pv.z - c1z;
                    d21 = dx1 * dx1 + dy1 * dy1 + dz1 * dz1;
                }
                const bool in0 = valid && (d20 < r2);
                const bool in1 = valid && (d21 < r2);
                const unsigned long long m0 = __ballot(in0);
                const unsigned long long m1 = __ballot(in1);
                const int id = __float_as_int(pv.w);
                if (in0) {
                    const int pos = K0 + __popcll(m0 & lanemask_lt);
                    if (pos < CAP) cand0[pos] = id;
                }
                if (in1) {
                    const int pos = K1 + __popcll(m1 & lanemask_lt);
                    if (pos < CAP) cand1[pos] = id;
                }
                K0 += __popcll(m0);
                K1 += __popcll(m1);
            }
        }
    }

    if (K0 > CAP) {
        linear_ball_fallback(xyz + (size_t)b * N * 3, c0x, c0y, c0z, lane, lanemask_lt, out0);
    } else {
        rank_select(cand0, K0, lane, out0);
    }
    if (K1 > CAP) {
        linear_ball_fallback(xyz + (size_t)b * N * 3, c1x, c1y, c1z, lane, lanemask_lt, out1);
    } else {
        rank_select(cand1, K1, lane, out1);
    }
}

// ---------------- Kernel 2: grouping, sorted queries + XCD swizzle ----------------
__global__ void __launch_bounds__(256) group2_kernel(
    const float* __restrict__ xyz, const float* __restrict__ new_xyz,
    const float* __restrict__ ft, const int* __restrict__ idx_arr,
    const int* __restrict__ qperm, float* __restrict__ out) {
    __shared__ int sidx[64];
    __shared__ float sf[64 * 65];

    const int t = threadIdx.x;
    const int g = blockIdx.x;                       // 0 .. B*NPOINT/2-1 (4096)
    const int nwg = B * NPOINT / 2;
    const int swz = (g & 7) * (nwg / 8) + (g >> 3); // bijective: nwg % 8 == 0
    const int b = swz / (NPOINT / 2);
    const int p = swz - b * (NPOINT / 2);

    const int q0 = qperm[b * NPOINT + 2 * p + 0];   // broadcast loads
    const int q1 = qperm[b * NPOINT + 2 * p + 1];

    if (t < 64) {
        const int qq = (t < 32) ? q0 : q1;
        sidx[t] = idx_arr[((size_t)b * NPOINT + qq) * NSAMPLE + (t & 31)];
    }
    __syncthreads();

    // Phase 1: gather features. pair p <- 16 lanes, each lane one float4.
    {
        const int lane16 = t & 15;
        const int pq = t >> 4;
#pragma unroll
        for (int it = 0; it < 4; ++it) {
            const int pp = it * 16 + pq;
            const int id = sidx[pp];
            const float4 v = *(const float4*)(ft + ((size_t)b * N + id) * C + lane16 * 4);
            float* dst = sf + pp * 65 + lane16 * 4;
            dst[0] = v.x; dst[1] = v.y; dst[2] = v.z; dst[3] = v.w;
        }
    }

    const size_t plane = (size_t)NPOINT * NSAMPLE;
    const size_t bbase = (size_t)b * (3 + C) * plane;

    // xyz part: pair index = t (threads 0..63)
    if (t < 64) {
        const int id = sidx[t];
        const int qq = (t < 32) ? q0 : q1;
        const size_t cb = ((size_t)b * NPOINT + qq) * 3;
        const size_t pb = ((size_t)b * N + id) * 3;
        const size_t ob = bbase + (size_t)qq * NSAMPLE + (t & 31);
        {
#pragma clang fp contract(off)
            out[ob + 0 * plane] = xyz[pb + 0] - new_xyz[cb + 0];
            out[ob + 1 * plane] = xyz[pb + 1] - new_xyz[cb + 1];
            out[ob + 2 * plane] = xyz[pb + 2] - new_xyz[cb + 2];
        }
    }
    __syncthreads();

    // Phase 2: wave w writes channel c = it*4+w; lanes 0-31 -> q0 row, 32-63 -> q1 row.
    const int l = t & 63;
    const int w = t >> 6;
    const int qq = (l < 32) ? q0 : q1;
    const size_t rowbase = bbase + (size_t)qq * NSAMPLE + (l & 31);
#pragma unroll
    for (int it = 0; it < 16; ++it) {
        const int c = it * 4 + w;
        out[rowbase + (size_t)(3 + c) * plane] = sf[l * 65 + c];
    }
}

// ---------------- ws-too-small fallbacks ----------------
__global__ void __launch_bounds__(256) ball_query_kernel(
    const float* __restrict__ xyz, const float* __restrict__ new_xyz,
    int* __restrict__ idx_out)
{
    const int wave = (blockIdx.x * blockDim.x + threadIdx.x) >> 6;
    const int lane = threadIdx.x & 63;
    if (wave >= B * NPOINT) return;
    const int b = wave / NPOINT;
    const float cx = new_xyz[(size_t)wave * 3 + 0];
    const float cy = new_xyz[(size_t)wave * 3 + 1];
    const float cz = new_xyz[(size_t)wave * 3 + 2];
    const unsigned long long lanemask_lt = (lane == 63) ? 0x7FFFFFFFFFFFFFFFull
                                                        : ((1ull << lane) - 1ull);
    linear_ball_fallback(xyz + (size_t)b * N * 3, cx, cy, cz, lane, lanemask_lt,
                         idx_out + (size_t)wave * NSAMPLE);
}

__global__ void __launch_bounds__(256) group_kernel(
    const float* __restrict__ xyz, const float* __restrict__ new_xyz,
    const float* __restrict__ feat, const int* __restrict__ idx_arr,
    float* __restrict__ out) {
    const int t = threadIdx.x;
    const int s = t & 31;
    const int jl = t >> 5;
    const int j = blockIdx.x * 8 + jl;
    const int b = blockIdx.y;

    const int id = idx_arr[((size_t)b * NPOINT + j) * NSAMPLE + s];

    const float px = xyz[((size_t)b * N + id) * 3 + 0] - new_xyz[((size_t)b * NPOINT + j) * 3 + 0];
    const float py = xyz[((size_t)b * N + id) * 3 + 1] - new_xyz[((size_t)b * NPOINT + j) * 3 + 1];
    const float pz = xyz[((size_t)b * N + id) * 3 + 2] - new_xyz[((size_t)b * NPOINT + j) * 3 + 2];

    const size_t plane = (size_t)NPOINT * NSAMPLE;
    const size_t obase = (size_t)b * (3 + C) * plane + (size_t)j * NSAMPLE + s;

    out[obase + 0 * plane] = px;
    out[obase + 1 * plane] = py;
    out[obase + 2 * plane] = pz;

    const float* __restrict__ fb = feat + (size_t)b * C * N;
#pragma unroll 8
    for (int c = 0; c < C; ++c) {
        out[obase + (size_t)(3 + c) * plane] = fb[(size_t)c * N + id];
    }
}

extern "C" void kernel_launch(void* const* d_in, const int* in_sizes, int n_in,
                              void* d_out, int out_size, void* d_ws, size_t ws_size,
                              hipStream_t stream) {
    const float* xyz     = (const float*)d_in[0];  // (B, N, 3)
    const float* new_xyz = (const float*)d_in[1];  // (B, NPOINT, 3)
    const float* feat    = (const float*)d_in[2];  // (B, C, N)
    float* out = (float*)d_out;

    // Workspace layout (contiguous)
    const size_t idx_bytes    = (size_t)B * NPOINT * NSAMPLE * sizeof(int);  // 1,048,576
    const size_t ft_bytes     = (size_t)B * N * C * sizeof(float);           // 8,388,608
    const size_t binned_bytes = (size_t)B * N * sizeof(float4);              //   524,288
    const size_t off_bytes    = (size_t)B * OFF_STRIDE * sizeof(int);        //     8,448
    const size_t qperm_bytes  = (size_t)B * NPOINT * sizeof(int);            //    32,768

    char* ws = (char*)d_ws;
    size_t o = 0;
    int*    idx_ws = (int*)(ws + o);    o += idx_bytes;
    float*  ft     = (float*)(ws + o);  o += ft_bytes;
    float4* binned = (float4*)(ws + o); o += binned_bytes;
    int*    off    = (int*)(ws + o);    o += off_bytes;
    int*    qperm  = (int*)(ws + o);    o += qperm_bytes;

    const bool use_grid = (ws_size >= o);

    if (use_grid) {
        prep_kernel<<<NTILE_BLOCKS + B, 1024, 0, stream>>>(
            feat, xyz, new_xyz, ft, binned, off, qperm);
        ball_query_pair_kernel<<<B * NPOINT / 8, 256, 0, stream>>>(
            binned, off, new_xyz, xyz, qperm, idx_ws);
        group2_kernel<<<B * NPOINT / 2, 256, 0, stream>>>(
            xyz, new_xyz, ft, idx_ws, qperm, out);
    } else {
        ball_query_kernel<<<(B * NPOINT) / 4, 256, 0, stream>>>(xyz, new_xyz, idx_ws);
        dim3 grid2(NPOINT / 8, B);
        group_kernel<<<grid2, 256, 0, stream>>>(xyz, new_xyz, feat, idx_ws, out);
    }
}

// Round 11
// 56.655 us; speedup vs baseline: 1.5925x; 1.5925x over previous
//
#include <hip/hip_runtime.h>

#define B 2
#define N 16384
#define NPOINT 4096
#define C 64
#define NSAMPLE 32

#define NCELL 1000        // 10x10x10 grid, cell size 0.1 == radius
#define CELLW_STRIDE 1024 // work array stride per batch
#define OFF_STRIDE 1056   // offsets stride per batch (1001 used)
#define CAP 192           // per-query candidate capacity (mean ~69)

// Threshold exactly as the JAX/numpy reference sees it:
// float32(double(0.1)*double(0.1)) = 0.009999999776482582f
__device__ __forceinline__ float r2_thresh() { return (float)(0.1 * 0.1); }

__device__ __forceinline__ int clamp09(int v) { return v < 0 ? 0 : (v > 9 ? 9 : v); }

__device__ __forceinline__ int cell_of(float x, float y, float z) {
    const int ix = clamp09((int)floorf(x * 10.0f));
    const int iy = clamp09((int)floorf(y * 10.0f));
    const int iz = clamp09((int)floorf(z * 10.0f));
    return (ix * 10 + iy) * 10 + iz;
}

// ---------------- Grid + query-sort build (4 small kernels, proven ~6us) ----------------
__global__ void __launch_bounds__(256) grid_init_kernel(int* __restrict__ work) {
    const int t = blockIdx.x * blockDim.x + threadIdx.x;
    if (t < 2 * B * CELLW_STRIDE) work[t] = 0;  // cellwork then qwork (adjacent)
}

__global__ void __launch_bounds__(256) grid_hist_kernel(
    const float* __restrict__ xyz, const float* __restrict__ new_xyz,
    int* __restrict__ cellwork, int* __restrict__ qwork) {
    const int i = blockIdx.x * blockDim.x + threadIdx.x;  // over B*(N+NPOINT)
    if (i < B * N) {
        const int b = i / N;
        const float x = xyz[(size_t)i * 3 + 0];
        const float y = xyz[(size_t)i * 3 + 1];
        const float z = xyz[(size_t)i * 3 + 2];
        atomicAdd(&cellwork[b * CELLW_STRIDE + cell_of(x, y, z)], 1);
    } else if (i < B * (N + NPOINT)) {
        const int qi = i - B * N;
        const int b = qi / NPOINT;
        const float x = new_xyz[(size_t)qi * 3 + 0];
        const float y = new_xyz[(size_t)qi * 3 + 1];
        const float z = new_xyz[(size_t)qi * 3 + 2];
        atomicAdd(&qwork[b * CELLW_STRIDE + cell_of(x, y, z)], 1);
    }
}

// 2B blocks: [0,B) point counts -> off + cursors; [B,2B) query counts -> cursors.
__global__ void __launch_bounds__(1024) grid_scan_kernel(
    int* __restrict__ cellwork, int* __restrict__ qwork, int* __restrict__ off) {
    __shared__ int s[1024];
    const int blk = blockIdx.x;
    const int t = threadIdx.x;
    int* __restrict__ arr = (blk < B) ? (cellwork + blk * CELLW_STRIDE)
                                      : (qwork + (blk - B) * CELLW_STRIDE);
    const int v = (t < NCELL) ? arr[t] : 0;
    s[t] = v;
    __syncthreads();
#pragma unroll
    for (int d = 1; d < 1024; d <<= 1) {
        const int add = (t >= d) ? s[t - d] : 0;
        __syncthreads();
        s[t] += add;
        __syncthreads();
    }
    const int excl = s[t] - v;
    if (blk < B && t <= NCELL) off[blk * OFF_STRIDE + t] = excl;  // off[1000] = N
    if (t < NCELL) arr[t] = excl;  // cursors for scatter
}

__global__ void __launch_bounds__(256) grid_scatter_kernel(
    const float* __restrict__ xyz, const float* __restrict__ new_xyz,
    int* __restrict__ cellwork, int* __restrict__ qwork,
    float4* __restrict__ binned, int* __restrict__ qperm) {
    const int i = blockIdx.x * blockDim.x + threadIdx.x;
    if (i < B * N) {
        const int b = i / N;
        const int p = i - b * N;
        const float x = xyz[(size_t)i * 3 + 0];
        const float y = xyz[(size_t)i * 3 + 1];
        const float z = xyz[(size_t)i * 3 + 2];
        const int c = cell_of(x, y, z);
        const int pos = atomicAdd(&cellwork[b * CELLW_STRIDE + c], 1);
        float4 v;
        v.x = x; v.y = y; v.z = z; v.w = __int_as_float(p);
        binned[(size_t)b * N + pos] = v;
    } else if (i < B * (N + NPOINT)) {
        const int qi = i - B * N;
        const int b = qi / NPOINT;
        const int j = qi - b * NPOINT;
        const float x = new_xyz[(size_t)qi * 3 + 0];
        const float y = new_xyz[(size_t)qi * 3 + 1];
        const float z = new_xyz[(size_t)qi * 3 + 2];
        const int c = cell_of(x, y, z);
        const int pos = atomicAdd(&qwork[b * CELLW_STRIDE + c], 1);
        qperm[b * NPOINT + pos] = j;
    }
}

// ---------------- exact linear-scan fallback (in-wave) ----------------
__device__ void linear_ball_fallback(const float* __restrict__ xb,
                                     float cx, float cy, float cz,
                                     int lane, unsigned long long lanemask_lt,
                                     int* out) {
    const float r2 = r2_thresh();
    int cnt = 0, first_idx = 0;
    for (int base = 0; base < N; base += 64) {
        const int i = base + lane;
        const float x = xb[i * 3 + 0];
        const float y = xb[i * 3 + 1];
        const float z = xb[i * 3 + 2];
        float d2;
        {
#pragma clang fp contract(off)
            float dx = x - cx;
            float dy = y - cy;
            float dz = z - cz;
            d2 = dx * dx + dy * dy + dz * dz;
        }
        const bool in = d2 < r2;
        const unsigned long long m = __ballot(in);
        if (in) {
            const int pos = cnt + __popcll(m & lanemask_lt);
            if (pos < NSAMPLE) out[pos] = i;
        }
        if (cnt == 0 && m != 0ull) first_idx = base + __builtin_ctzll(m);
        cnt += __popcll(m);
        if (cnt >= NSAMPLE) break;
    }
    if (cnt < NSAMPLE) {
        if (cnt == 0) first_idx = 0;
        for (int pos = cnt + lane; pos < NSAMPLE; pos += 64) out[pos] = first_idx;
    }
}

// Rank-select the NSAMPLE smallest indices from cand[0..K) (K <= CAP) -> out.
__device__ __forceinline__ void rank_select(const int* cand, int K, int lane,
                                            int* __restrict__ out) {
    const int e0 = (lane < K) ? cand[lane] : 0x7FFFFFFF;
    const int e1 = (64 + lane < K) ? cand[64 + lane] : 0x7FFFFFFF;
    const int e2 = (128 + lane < K) ? cand[128 + lane] : 0x7FFFFFFF;
    int r0 = 0, r1 = 0, r2i = 0;
    if (K <= 64) {
        for (int k = 0; k < K; ++k) { const int v = cand[k]; r0 += (v < e0); }
    } else if (K <= 128) {
        for (int k = 0; k < K; ++k) { const int v = cand[k]; r0 += (v < e0); r1 += (v < e1); }
    } else {
        for (int k = 0; k < K; ++k) {
            const int v = cand[k];
            r0 += (v < e0); r1 += (v < e1); r2i += (v < e2);
        }
    }
    if (lane < K && r0 < NSAMPLE) out[r0] = e0;
    if (64 + lane < K && r1 < NSAMPLE) out[r1] = e1;
    if (128 + lane < K && r2i < NSAMPLE) out[r2i] = e2;

    if (K < NSAMPLE) {
        int mn = min(e0, min(e1, e2));
#pragma unroll
        for (int d = 32; d; d >>= 1) mn = min(mn, __shfl_xor(mn, d));
        const int fill = (K > 0) ? mn : 0;
        for (int pos = K + lane; pos < NSAMPLE; pos += 64) out[pos] = fill;
    }
}

// Scan one window against one center; append in-ball ids to cand; returns K.
__device__ __forceinline__ int scan_window(
    const float4* __restrict__ bb, const int* __restrict__ ob,
    int lox, int hix, int loy, int hiy, int loz, int hiz,
    float cx, float cy, float cz, int lane,
    unsigned long long lanemask_lt, int* cand)
{
    const float r2 = r2_thresh();
    int K = 0;
    for (int ix = lox; ix <= hix; ++ix) {
        for (int iy = loy; iy <= hiy; ++iy) {
            const int rowc = (ix * 10 + iy) * 10;
            const int s0 = ob[rowc + loz];
            const int s1 = ob[rowc + hiz + 1];  // z cells contiguous -> one segment
            for (int cur = s0; cur < s1; cur += 64) {
                const int i = cur + lane;
                const bool valid = (i < s1);
                float4 pv;
                if (valid) pv = bb[i];
                else { pv.x = 1e9f; pv.y = 1e9f; pv.z = 1e9f; pv.w = 0.0f; }
                float d2;
                {
#pragma clang fp contract(off)
                    float dx = pv.x - cx, dy = pv.y - cy, dz = pv.z - cz;
                    d2 = dx * dx + dy * dy + dz * dz;
                }
                const bool in = valid && (d2 < r2);
                const unsigned long long m = __ballot(in);
                if (in) {
                    const int pos = K + __popcll(m & lanemask_lt);
                    if (pos < CAP) cand[pos] = __float_as_int(pv.w);
                }
                K += __popcll(m);
            }
        }
    }
    return K;
}

// ---------------- Kernel 1g: ball query, TWO sorted queries per wave, guarded ----------------
// If both queries have IDENTICAL windows (typical: same cell -> same 3^3
// neighborhood since radius == cell size), one shared scan tests both centers
// (loads amortized 2x). Otherwise two bounded sequential scans — no straggler
// unions (round-10 lesson).
__global__ void __launch_bounds__(256) ball_query_pair_kernel(
    const float4* __restrict__ binned,   // (B, N) {x,y,z,idx}
    const int* __restrict__ off,         // (B, OFF_STRIDE)
    const float* __restrict__ new_xyz,   // (B, NPOINT, 3)
    const float* __restrict__ xyz,       // (B, N, 3) overflow fallback
    const int* __restrict__ qperm,       // (B, NPOINT)
    int* __restrict__ idx_out)           // (B, NPOINT, NSAMPLE)
{
    __shared__ int cand_s[8][CAP];      // 4 waves x 2 queries
    const int lane = threadIdx.x & 63;
    const int wib = threadIdx.x >> 6;

    const int nwg = B * NPOINT / 8;                 // 1024 blocks, % 8 == 0
    const int g = blockIdx.x;
    const int swz = (g & 7) * (nwg / 8) + (g >> 3); // bijective XCD swizzle
    const int gw = swz * 4 + wib;                   // pair id over 4096
    const int b = gw / (NPOINT / 2);
    const int r = gw % (NPOINT / 2);

    const int j0 = qperm[b * NPOINT + 2 * r + 0];   // broadcast loads
    const int j1 = qperm[b * NPOINT + 2 * r + 1];

    const float c0x = new_xyz[((size_t)b * NPOINT + j0) * 3 + 0];
    const float c0y = new_xyz[((size_t)b * NPOINT + j0) * 3 + 1];
    const float c0z = new_xyz[((size_t)b * NPOINT + j0) * 3 + 2];
    const float c1x = new_xyz[((size_t)b * NPOINT + j1) * 3 + 0];
    const float c1y = new_xyz[((size_t)b * NPOINT + j1) * 3 + 1];
    const float c1z = new_xyz[((size_t)b * NPOINT + j1) * 3 + 2];

    int* cand0 = cand_s[wib * 2 + 0];
    int* cand1 = cand_s[wib * 2 + 1];
    const float4* __restrict__ bb = binned + (size_t)b * N;
    const int* __restrict__ ob = off + b * OFF_STRIDE;
    int* __restrict__ out0 = idx_out + ((size_t)b * NPOINT + j0) * NSAMPLE;
    int* __restrict__ out1 = idx_out + ((size_t)b * NPOINT + j1) * NSAMPLE;

    const float r2 = r2_thresh();
    const unsigned long long lanemask_lt = (lane == 63) ? 0x7FFFFFFFFFFFFFFFull
                                                        : ((1ull << lane) - 1ull);

    // Per-query windows (each ~3 cells/axis; radius == cell size)
    const int l0x = max(0, (int)floorf((c0x - 0.1001f) * 10.0f));
    const int h0x = min(9, (int)floorf((c0x + 0.1001f) * 10.0f));
    const int l0y = max(0, (int)floorf((c0y - 0.1001f) * 10.0f));
    const int h0y = min(9, (int)floorf((c0y + 0.1001f) * 10.0f));
    const int l0z = max(0, (int)floorf((c0z - 0.1001f) * 10.0f));
    const int h0z = min(9, (int)floorf((c0z + 0.1001f) * 10.0f));
    const int l1x = max(0, (int)floorf((c1x - 0.1001f) * 10.0f));
    const int h1x = min(9, (int)floorf((c1x + 0.1001f) * 10.0f));
    const int l1y = max(0, (int)floorf((c1y - 0.1001f) * 10.0f));
    const int h1y = min(9, (int)floorf((c1y + 0.1001f) * 10.0f));
    const int l1z = max(0, (int)floorf((c1z - 0.1001f) * 10.0f));
    const int h1z = min(9, (int)floorf((c1z + 0.1001f) * 10.0f));

    const bool same_window = (l0x == l1x) && (h0x == h1x) &&
                             (l0y == l1y) && (h0y == h1y) &&
                             (l0z == l1z) && (h0z == h1z);

    int K0 = 0, K1 = 0;
    if (same_window) {
        // Shared scan: each chunk loaded once, tested against both centers.
        for (int ix = l0x; ix <= h0x; ++ix) {
            for (int iy = l0y; iy <= h0y; ++iy) {
                const int rowc = (ix * 10 + iy) * 10;
                const int s0 = ob[rowc + l0z];
                const int s1 = ob[rowc + h0z + 1];
                for (int cur = s0; cur < s1; cur += 64) {
                    const int i = cur + lane;
                    const bool valid = (i < s1);
                    float4 pv;
                    if (valid) pv = bb[i];
                    else { pv.x = 1e9f; pv.y = 1e9f; pv.z = 1e9f; pv.w = 0.0f; }
                    float d20, d21;
                    {
#pragma clang fp contract(off)
                        float dx0 = pv.x - c0x, dy0 = pv.y - c0y, dz0 = pv.z - c0z;
                        d20 = dx0 * dx0 + dy0 * dy0 + dz0 * dz0;
                        float dx1 = pv.x - c1x, dy1 = pv.y - c1y, dz1 = pv.z - c1z;
                        d21 = dx1 * dx1 + dy1 * dy1 + dz1 * dz1;
                    }
                    const bool in0 = valid && (d20 < r2);
                    const bool in1 = valid && (d21 < r2);
                    const unsigned long long m0 = __ballot(in0);
                    const unsigned long long m1 = __ballot(in1);
                    const int id = __float_as_int(pv.w);
                    if (in0) {
                        const int pos = K0 + __popcll(m0 & lanemask_lt);
                        if (pos < CAP) cand0[pos] = id;
                    }
                    if (in1) {
                        const int pos = K1 + __popcll(m1 & lanemask_lt);
                        if (pos < CAP) cand1[pos] = id;
                    }
                    K0 += __popcll(m0);
                    K1 += __popcll(m1);
                }
            }
        }
    } else {
        // Bounded sequential scans (each <= 27 cells; no union blow-up).
        K0 = scan_window(bb, ob, l0x, h0x, l0y, h0y, l0z, h0z,
                         c0x, c0y, c0z, lane, lanemask_lt, cand0);
        K1 = scan_window(bb, ob, l1x, h1x, l1y, h1y, l1z, h1z,
                         c1x, c1y, c1z, lane, lanemask_lt, cand1);
    }

    if (K0 > CAP) {
        linear_ball_fallback(xyz + (size_t)b * N * 3, c0x, c0y, c0z, lane, lanemask_lt, out0);
    } else {
        rank_select(cand0, K0, lane, out0);
    }
    if (K1 > CAP) {
        linear_ball_fallback(xyz + (size_t)b * N * 3, c1x, c1y, c1z, lane, lanemask_lt, out1);
    } else {
        rank_select(cand1, K1, lane, out1);
    }
}

// ---------------- Kernel T: transpose features (B,C,N) -> (B,N,C) ----------------
__global__ void __launch_bounds__(256) transpose_kernel(
    const float* __restrict__ feat, float* __restrict__ ft) {
    __shared__ float tile[64 * 65];
    const int b = blockIdx.y;
    const int n0 = blockIdx.x * 64;
    const int t = threadIdx.x;
    const int l = t & 63;
    const int w = t >> 6;
#pragma unroll
    for (int it = 0; it < 16; ++it) {
        const int c = it * 4 + w;
        tile[c * 65 + l] = feat[((size_t)b * C + c) * N + n0 + l];
    }
    __syncthreads();
#pragma unroll
    for (int it = 0; it < 16; ++it) {
        const int nn = it * 4 + w;
        ft[((size_t)b * N + n0 + nn) * C + l] = tile[l * 65 + nn];
    }
}

// ---------------- Kernel 2: grouping, sorted queries + XCD swizzle ----------------
__global__ void __launch_bounds__(256) group2_kernel(
    const float* __restrict__ xyz, const float* __restrict__ new_xyz,
    const float* __restrict__ ft, const int* __restrict__ idx_arr,
    const int* __restrict__ qperm, float* __restrict__ out) {
    __shared__ int sidx[64];
    __shared__ float sf[64 * 65];

    const int t = threadIdx.x;
    const int g = blockIdx.x;                       // 0 .. B*NPOINT/2-1 (4096)
    const int nwg = B * NPOINT / 2;
    const int swz = (g & 7) * (nwg / 8) + (g >> 3); // bijective: nwg % 8 == 0
    const int b = swz / (NPOINT / 2);
    const int p = swz - b * (NPOINT / 2);

    const int q0 = qperm[b * NPOINT + 2 * p + 0];   // broadcast loads
    const int q1 = qperm[b * NPOINT + 2 * p + 1];

    if (t < 64) {
        const int qq = (t < 32) ? q0 : q1;
        sidx[t] = idx_arr[((size_t)b * NPOINT + qq) * NSAMPLE + (t & 31)];
    }
    __syncthreads();

    // Phase 1: gather features. pair p <- 16 lanes, each lane one float4.
    {
        const int lane16 = t & 15;
        const int pq = t >> 4;
#pragma unroll
        for (int it = 0; it < 4; ++it) {
            const int pp = it * 16 + pq;
            const int id = sidx[pp];
            const float4 v = *(const float4*)(ft + ((size_t)b * N + id) * C + lane16 * 4);
            float* dst = sf + pp * 65 + lane16 * 4;
            dst[0] = v.x; dst[1] = v.y; dst[2] = v.z; dst[3] = v.w;
        }
    }

    const size_t plane = (size_t)NPOINT * NSAMPLE;
    const size_t bbase = (size_t)b * (3 + C) * plane;

    // xyz part: pair index = t (threads 0..63)
    if (t < 64) {
        const int id = sidx[t];
        const int qq = (t < 32) ? q0 : q1;
        const size_t cb = ((size_t)b * NPOINT + qq) * 3;
        const size_t pb = ((size_t)b * N + id) * 3;
        const size_t ob = bbase + (size_t)qq * NSAMPLE + (t & 31);
        {
#pragma clang fp contract(off)
            out[ob + 0 * plane] = xyz[pb + 0] - new_xyz[cb + 0];
            out[ob + 1 * plane] = xyz[pb + 1] - new_xyz[cb + 1];
            out[ob + 2 * plane] = xyz[pb + 2] - new_xyz[cb + 2];
        }
    }
    __syncthreads();

    // Phase 2: wave w writes channel c = it*4+w; lanes 0-31 -> q0 row, 32-63 -> q1 row.
    const int l = t & 63;
    const int w = t >> 6;
    const int qq = (l < 32) ? q0 : q1;
    const size_t rowbase = bbase + (size_t)qq * NSAMPLE + (l & 31);
#pragma unroll
    for (int it = 0; it < 16; ++it) {
        const int c = it * 4 + w;
        out[rowbase + (size_t)(3 + c) * plane] = sf[l * 65 + c];
    }
}

// ---------------- ws-too-small fallbacks ----------------
__global__ void __launch_bounds__(256) ball_query_kernel(
    const float* __restrict__ xyz, const float* __restrict__ new_xyz,
    int* __restrict__ idx_out)
{
    const int wave = (blockIdx.x * blockDim.x + threadIdx.x) >> 6;
    const int lane = threadIdx.x & 63;
    if (wave >= B * NPOINT) return;
    const int b = wave / NPOINT;
    const float cx = new_xyz[(size_t)wave * 3 + 0];
    const float cy = new_xyz[(size_t)wave * 3 + 1];
    const float cz = new_xyz[(size_t)wave * 3 + 2];
    const unsigned long long lanemask_lt = (lane == 63) ? 0x7FFFFFFFFFFFFFFFull
                                                        : ((1ull << lane) - 1ull);
    linear_ball_fallback(xyz + (size_t)b * N * 3, cx, cy, cz, lane, lanemask_lt,
                         idx_out + (size_t)wave * NSAMPLE);
}

__global__ void __launch_bounds__(256) group_kernel(
    const float* __restrict__ xyz, const float* __restrict__ new_xyz,
    const float* __restrict__ feat, const int* __restrict__ idx_arr,
    float* __restrict__ out) {
    const int t = threadIdx.x;
    const int s = t & 31;
    const int jl = t >> 5;
    const int j = blockIdx.x * 8 + jl;
    const int b = blockIdx.y;

    const int id = idx_arr[((size_t)b * NPOINT + j) * NSAMPLE + s];

    const float px = xyz[((size_t)b * N + id) * 3 + 0] - new_xyz[((size_t)b * NPOINT + j) * 3 + 0];
    const float py = xyz[((size_t)b * N + id) * 3 + 1] - new_xyz[((size_t)b * NPOINT + j) * 3 + 1];
    const float pz = xyz[((size_t)b * N + id) * 3 + 2] - new_xyz[((size_t)b * NPOINT + j) * 3 + 2];

    const size_t plane = (size_t)NPOINT * NSAMPLE;
    const size_t obase = (size_t)b * (3 + C) * plane + (size_t)j * NSAMPLE + s;

    out[obase + 0 * plane] = px;
    out[obase + 1 * plane] = py;
    out[obase + 2 * plane] = pz;

    const float* __restrict__ fb = feat + (size_t)b * C * N;
#pragma unroll 8
    for (int c = 0; c < C; ++c) {
        out[obase + (size_t)(3 + c) * plane] = fb[(size_t)c * N + id];
    }
}

extern "C" void kernel_launch(void* const* d_in, const int* in_sizes, int n_in,
                              void* d_out, int out_size, void* d_ws, size_t ws_size,
                              hipStream_t stream) {
    const float* xyz     = (const float*)d_in[0];  // (B, N, 3)
    const float* new_xyz = (const float*)d_in[1];  // (B, NPOINT, 3)
    const float* feat    = (const float*)d_in[2];  // (B, C, N)
    float* out = (float*)d_out;

    // Workspace layout (contiguous)
    const size_t idx_bytes    = (size_t)B * NPOINT * NSAMPLE * sizeof(int);  // 1,048,576
    const size_t ft_bytes     = (size_t)B * N * C * sizeof(float);           // 8,388,608
    const size_t binned_bytes = (size_t)B * N * sizeof(float4);              //   524,288
    const size_t off_bytes    = (size_t)B * OFF_STRIDE * sizeof(int);        //     8,448
    const size_t cellw_bytes  = (size_t)B * CELLW_STRIDE * sizeof(int);      //     8,192
    const size_t qwork_bytes  = (size_t)B * CELLW_STRIDE * sizeof(int);      //     8,192
    const size_t qperm_bytes  = (size_t)B * NPOINT * sizeof(int);            //    32,768

    char* ws = (char*)d_ws;
    size_t o = 0;
    int*    idx_ws   = (int*)(ws + o);    o += idx_bytes;
    float*  ft       = (float*)(ws + o);  o += ft_bytes;
    float4* binned   = (float4*)(ws + o); o += binned_bytes;
    int*    off      = (int*)(ws + o);    o += off_bytes;
    int*    cellwork = (int*)(ws + o);    o += cellw_bytes;   // cellwork+qwork adjacent
    int*    qwork    = (int*)(ws + o);    o += qwork_bytes;
    int*    qperm    = (int*)(ws + o);    o += qperm_bytes;

    const bool use_grid = (ws_size >= o);

    if (use_grid) {
        transpose_kernel<<<dim3(N / 64, B), 256, 0, stream>>>(feat, ft);
        grid_init_kernel<<<(2 * B * CELLW_STRIDE + 255) / 256, 256, 0, stream>>>(cellwork);
        grid_hist_kernel<<<(B * (N + NPOINT) + 255) / 256, 256, 0, stream>>>(
            xyz, new_xyz, cellwork, qwork);
        grid_scan_kernel<<<2 * B, 1024, 0, stream>>>(cellwork, qwork, off);
        grid_scatter_kernel<<<(B * (N + NPOINT) + 255) / 256, 256, 0, stream>>>(
            xyz, new_xyz, cellwork, qwork, binned, qperm);
        ball_query_pair_kernel<<<B * NPOINT / 8, 256, 0, stream>>>(
            binned, off, new_xyz, xyz, qperm, idx_ws);
        group2_kernel<<<B * NPOINT / 2, 256, 0, stream>>>(
            xyz, new_xyz, ft, idx_ws, qperm, out);
    } else {
        ball_query_kernel<<<(B * NPOINT) / 4, 256, 0, stream>>>(xyz, new_xyz, idx_ws);
        dim3 grid2(NPOINT / 8, B);
        group_kernel<<<grid2, 256, 0, stream>>>(xyz, new_xyz, feat, idx_ws, out);
    }
}

// Round 12
// 52.548 us; speedup vs baseline: 1.7170x; 1.0782x over previous
//
#include <hip/hip_runtime.h>

#define B 2
#define N 16384
#define NPOINT 4096
#define C 64
#define NSAMPLE 32

#define NCELL 1000        // 10x10x10 grid, cell size 0.1 == radius
#define CELLW_STRIDE 1024 // work array stride per batch
#define OFF_STRIDE 1056   // offsets stride per batch (1001 used)
#define CAP 192           // per-query candidate capacity (mean ~69)

#define BALL_BLOCKS (B * NPOINT / 4)      // 2048 (4 queries per 256-thr block)
#define TRANS_BLOCKS (B * (N / 64))       // 512

// Threshold exactly as the JAX/numpy reference sees it:
// float32(double(0.1)*double(0.1)) = 0.009999999776482582f
__device__ __forceinline__ float r2_thresh() { return (float)(0.1 * 0.1); }

__device__ __forceinline__ int clamp09(int v) { return v < 0 ? 0 : (v > 9 ? 9 : v); }

__device__ __forceinline__ int cell_of(float x, float y, float z) {
    const int ix = clamp09((int)floorf(x * 10.0f));
    const int iy = clamp09((int)floorf(y * 10.0f));
    const int iz = clamp09((int)floorf(z * 10.0f));
    return (ix * 10 + iy) * 10 + iz;
}

// ---------------- Kernel H: histogram points AND queries ----------------
__global__ void __launch_bounds__(256) grid_hist_kernel(
    const float* __restrict__ xyz, const float* __restrict__ new_xyz,
    int* __restrict__ cellwork, int* __restrict__ qwork) {
    const int i = blockIdx.x * blockDim.x + threadIdx.x;  // over B*(N+NPOINT)
    if (i < B * N) {
        const int b = i / N;
        const float x = xyz[(size_t)i * 3 + 0];
        const float y = xyz[(size_t)i * 3 + 1];
        const float z = xyz[(size_t)i * 3 + 2];
        atomicAdd(&cellwork[b * CELLW_STRIDE + cell_of(x, y, z)], 1);
    } else if (i < B * (N + NPOINT)) {
        const int qi = i - B * N;
        const int b = qi / NPOINT;
        const float x = new_xyz[(size_t)qi * 3 + 0];
        const float y = new_xyz[(size_t)qi * 3 + 1];
        const float z = new_xyz[(size_t)qi * 3 + 2];
        atomicAdd(&qwork[b * CELLW_STRIDE + cell_of(x, y, z)], 1);
    }
}

// ---------------- Kernel S: shuffle-based exclusive scan (2 barriers) ----------------
// 2B blocks: [0,B) point counts -> off + cursors; [B,2B) query counts -> cursors.
__global__ void __launch_bounds__(1024) grid_scan_kernel(
    int* __restrict__ cellwork, int* __restrict__ qwork, int* __restrict__ off) {
    __shared__ int wsum[16];
    const int blk = blockIdx.x;
    const int t = threadIdx.x;
    const int lane = t & 63;
    const int w = t >> 6;   // 16 waves
    int* __restrict__ arr = (blk < B) ? (cellwork + blk * CELLW_STRIDE)
                                      : (qwork + (blk - B) * CELLW_STRIDE);
    const int v = (t < NCELL) ? arr[t] : 0;

    // inclusive wave scan via shuffles
    int s = v;
#pragma unroll
    for (int d = 1; d < 64; d <<= 1) {
        const int u = __shfl_up(s, d, 64);
        if (lane >= d) s += u;
    }
    if (lane == 63) wsum[w] = s;
    __syncthreads();
    if (w == 0) {
        int p = (lane < 16) ? wsum[lane] : 0;
#pragma unroll
        for (int d = 1; d < 16; d <<= 1) {
            const int u = __shfl_up(p, d, 64);
            if (lane >= d) p += u;
        }
        if (lane < 16) wsum[lane] = p;   // inclusive partial sums
    }
    __syncthreads();
    const int prefix = (w > 0) ? wsum[w - 1] : 0;
    const int excl = s + prefix - v;
    if (blk < B && t <= NCELL) off[blk * OFF_STRIDE + t] = excl;  // off[1000] = N
    if (t < NCELL) arr[t] = excl;  // cursors for scatter
}

// ---------------- Kernel C: scatter points + queries ----------------
__global__ void __launch_bounds__(256) grid_scatter_kernel(
    const float* __restrict__ xyz, const float* __restrict__ new_xyz,
    int* __restrict__ cellwork, int* __restrict__ qwork,
    float4* __restrict__ binned, int* __restrict__ qperm) {
    const int i = blockIdx.x * blockDim.x + threadIdx.x;
    if (i < B * N) {
        const int b = i / N;
        const int p = i - b * N;
        const float x = xyz[(size_t)i * 3 + 0];
        const float y = xyz[(size_t)i * 3 + 1];
        const float z = xyz[(size_t)i * 3 + 2];
        const int c = cell_of(x, y, z);
        const int pos = atomicAdd(&cellwork[b * CELLW_STRIDE + c], 1);
        float4 v;
        v.x = x; v.y = y; v.z = z; v.w = __int_as_float(p);
        binned[(size_t)b * N + pos] = v;
    } else if (i < B * (N + NPOINT)) {
        const int qi = i - B * N;
        const int b = qi / NPOINT;
        const int j = qi - b * NPOINT;
        const float x = new_xyz[(size_t)qi * 3 + 0];
        const float y = new_xyz[(size_t)qi * 3 + 1];
        const float z = new_xyz[(size_t)qi * 3 + 2];
        const int c = cell_of(x, y, z);
        const int pos = atomicAdd(&qwork[b * CELLW_STRIDE + c], 1);
        qperm[b * NPOINT + pos] = j;
    }
}

// ---------------- exact linear-scan fallback (in-wave) ----------------
__device__ void linear_ball_fallback(const float* __restrict__ xb,
                                     float cx, float cy, float cz,
                                     int lane, unsigned long long lanemask_lt,
                                     int* out) {
    const float r2 = r2_thresh();
    int cnt = 0, first_idx = 0;
    for (int base = 0; base < N; base += 64) {
        const int i = base + lane;
        const float x = xb[i * 3 + 0];
        const float y = xb[i * 3 + 1];
        const float z = xb[i * 3 + 2];
        float d2;
        {
#pragma clang fp contract(off)
            float dx = x - cx;
            float dy = y - cy;
            float dz = z - cz;
            d2 = dx * dx + dy * dy + dz * dz;
        }
        const bool in = d2 < r2;
        const unsigned long long m = __ballot(in);
        if (in) {
            const int pos = cnt + __popcll(m & lanemask_lt);
            if (pos < NSAMPLE) out[pos] = i;
        }
        if (cnt == 0 && m != 0ull) first_idx = base + __builtin_ctzll(m);
        cnt += __popcll(m);
        if (cnt >= NSAMPLE) break;
    }
    if (cnt < NSAMPLE) {
        if (cnt == 0) first_idx = 0;
        for (int pos = cnt + lane; pos < NSAMPLE; pos += 64) out[pos] = first_idx;
    }
}

// Rank-select the NSAMPLE smallest indices from cand[0..K) (K <= CAP) -> out.
__device__ __forceinline__ void rank_select(const int* cand, int K, int lane,
                                            int* __restrict__ out) {
    const int e0 = (lane < K) ? cand[lane] : 0x7FFFFFFF;
    const int e1 = (64 + lane < K) ? cand[64 + lane] : 0x7FFFFFFF;
    const int e2 = (128 + lane < K) ? cand[128 + lane] : 0x7FFFFFFF;
    int r0 = 0, r1 = 0, r2i = 0;
    if (K <= 64) {
        for (int k = 0; k < K; ++k) { const int v = cand[k]; r0 += (v < e0); }
    } else if (K <= 128) {
        for (int k = 0; k < K; ++k) { const int v = cand[k]; r0 += (v < e0); r1 += (v < e1); }
    } else {
        for (int k = 0; k < K; ++k) {
            const int v = cand[k];
            r0 += (v < e0); r1 += (v < e1); r2i += (v < e2);
        }
    }
    if (lane < K && r0 < NSAMPLE) out[r0] = e0;
    if (64 + lane < K && r1 < NSAMPLE) out[r1] = e1;
    if (128 + lane < K && r2i < NSAMPLE) out[r2i] = e2;

    if (K < NSAMPLE) {
        int mn = min(e0, min(e1, e2));
#pragma unroll
        for (int d = 32; d; d >>= 1) mn = min(mn, __shfl_xor(mn, d));
        const int fill = (K > 0) ? mn : 0;
        for (int pos = K + lane; pos < NSAMPLE; pos += 64) out[pos] = fill;
    }
}

// Scan one window against one center; append in-ball ids to cand; returns K.
__device__ __forceinline__ int scan_window(
    const float4* __restrict__ bb, const int* __restrict__ ob,
    int lox, int hix, int loy, int hiy, int loz, int hiz,
    float cx, float cy, float cz, int lane,
    unsigned long long lanemask_lt, int* cand)
{
    const float r2 = r2_thresh();
    int K = 0;
    for (int ix = lox; ix <= hix; ++ix) {
        for (int iy = loy; iy <= hiy; ++iy) {
            const int rowc = (ix * 10 + iy) * 10;
            const int s0 = ob[rowc + loz];
            const int s1 = ob[rowc + hiz + 1];  // z cells contiguous -> one segment
            for (int cur = s0; cur < s1; cur += 64) {
                const int i = cur + lane;
                const bool valid = (i < s1);
                float4 pv;
                if (valid) pv = bb[i];
                else { pv.x = 1e9f; pv.y = 1e9f; pv.z = 1e9f; pv.w = 0.0f; }
                float d2;
                {
#pragma clang fp contract(off)
                    float dx = pv.x - cx, dy = pv.y - cy, dz = pv.z - cz;
                    d2 = dx * dx + dy * dy + dz * dz;
                }
                const bool in = valid && (d2 < r2);
                const unsigned long long m = __ballot(in);
                if (in) {
                    const int pos = K + __popcll(m & lanemask_lt);
                    if (pos < CAP) cand[pos] = __float_as_int(pv.w);
                }
                K += __popcll(m);
            }
        }
    }
    return K;
}

// ---------------- Kernel B: ball query (blocks 0..2047) ∥ transpose (2048..2559) ----------------
// Independent work fused into one launch: transpose blocks dispatch after all
// ball blocks are resident, filling ball's straggler tail. Union LDS 19.7 KB
// -> 8 blocks/CU = 32 waves/CU (wave-limit, unchanged for both phases).
__global__ void __launch_bounds__(256) ball_and_transpose_kernel(
    const float4* __restrict__ binned,   // (B, N) {x,y,z,idx}
    const int* __restrict__ off,         // (B, OFF_STRIDE)
    const float* __restrict__ new_xyz,   // (B, NPOINT, 3)
    const float* __restrict__ xyz,       // (B, N, 3) overflow fallback
    const int* __restrict__ qperm,       // (B, NPOINT)
    int* __restrict__ idx_out,           // (B, NPOINT, NSAMPLE)
    const float* __restrict__ feat,      // (B, C, N)
    float* __restrict__ ft)              // (B, N, C)
{
    __shared__ int cand_s[4][CAP];
    __shared__ float tile[64 * 65];

    const int t = threadIdx.x;

    if (blockIdx.x >= BALL_BLOCKS) {
        // ---- transpose branch ----
        const int tb = blockIdx.x - BALL_BLOCKS;    // 0..511
        const int b = tb / (N / 64);
        const int n0 = (tb % (N / 64)) * 64;
        const int l = t & 63;
        const int w = t >> 6;
#pragma unroll
        for (int it = 0; it < 16; ++it) {
            const int c = it * 4 + w;
            tile[c * 65 + l] = feat[((size_t)b * C + c) * N + n0 + l];
        }
        __syncthreads();
#pragma unroll
        for (int it = 0; it < 16; ++it) {
            const int nn = it * 4 + w;
            ft[((size_t)b * N + n0 + nn) * C + l] = tile[l * 65 + nn];
        }
        return;
    }

    // ---- ball branch: one wave per sorted query ----
    const int lane = t & 63;
    const int wib = t >> 6;
    const int wave = blockIdx.x * 4 + wib;          // sorted position, 0..8191
    const int b = wave / NPOINT;
    const int sp = wave - b * NPOINT;
    const int j = qperm[b * NPOINT + sp];           // original query index

    const float cx = new_xyz[((size_t)b * NPOINT + j) * 3 + 0];
    const float cy = new_xyz[((size_t)b * NPOINT + j) * 3 + 1];
    const float cz = new_xyz[((size_t)b * NPOINT + j) * 3 + 2];

    int* cand = cand_s[wib];
    const float4* __restrict__ bb = binned + (size_t)b * N;
    const int* __restrict__ ob = off + b * OFF_STRIDE;
    int* __restrict__ out = idx_out + ((size_t)b * NPOINT + j) * NSAMPLE;

    const unsigned long long lanemask_lt = (lane == 63) ? 0x7FFFFFFFFFFFFFFFull
                                                        : ((1ull << lane) - 1ull);

    const int lox = max(0, (int)floorf((cx - 0.1001f) * 10.0f));
    const int hix = min(9, (int)floorf((cx + 0.1001f) * 10.0f));
    const int loy = max(0, (int)floorf((cy - 0.1001f) * 10.0f));
    const int hiy = min(9, (int)floorf((cy + 0.1001f) * 10.0f));
    const int loz = max(0, (int)floorf((cz - 0.1001f) * 10.0f));
    const int hiz = min(9, (int)floorf((cz + 0.1001f) * 10.0f));

    const int K = scan_window(bb, ob, lox, hix, loy, hiy, loz, hiz,
                              cx, cy, cz, lane, lanemask_lt, cand);

    if (K > CAP) {  // pathological density: exact linear rescan (wave-uniform)
        linear_ball_fallback(xyz + (size_t)b * N * 3, cx, cy, cz, lane, lanemask_lt, out);
    } else {
        rank_select(cand, K, lane, out);
    }
}

// ---------------- Kernel 2: grouping, sorted queries + XCD swizzle ----------------
__global__ void __launch_bounds__(256) group2_kernel(
    const float* __restrict__ xyz, const float* __restrict__ new_xyz,
    const float* __restrict__ ft, const int* __restrict__ idx_arr,
    const int* __restrict__ qperm, float* __restrict__ out) {
    __shared__ int sidx[64];
    __shared__ float sf[64 * 65];

    const int t = threadIdx.x;
    const int g = blockIdx.x;                       // 0 .. B*NPOINT/2-1 (4096)
    const int nwg = B * NPOINT / 2;
    const int swz = (g & 7) * (nwg / 8) + (g >> 3); // bijective: nwg % 8 == 0
    const int b = swz / (NPOINT / 2);
    const int p = swz - b * (NPOINT / 2);

    const int q0 = qperm[b * NPOINT + 2 * p + 0];   // broadcast loads
    const int q1 = qperm[b * NPOINT + 2 * p + 1];

    if (t < 64) {
        const int qq = (t < 32) ? q0 : q1;
        sidx[t] = idx_arr[((size_t)b * NPOINT + qq) * NSAMPLE + (t & 31)];
    }
    __syncthreads();

    // Phase 1: gather features. pair p <- 16 lanes, each lane one float4.
    {
        const int lane16 = t & 15;
        const int pq = t >> 4;
#pragma unroll
        for (int it = 0; it < 4; ++it) {
            const int pp = it * 16 + pq;
            const int id = sidx[pp];
            const float4 v = *(const float4*)(ft + ((size_t)b * N + id) * C + lane16 * 4);
            float* dst = sf + pp * 65 + lane16 * 4;
            dst[0] = v.x; dst[1] = v.y; dst[2] = v.z; dst[3] = v.w;
        }
    }

    const size_t plane = (size_t)NPOINT * NSAMPLE;
    const size_t bbase = (size_t)b * (3 + C) * plane;

    // xyz part: pair index = t (threads 0..63)
    if (t < 64) {
        const int id = sidx[t];
        const int qq = (t < 32) ? q0 : q1;
        const size_t cb = ((size_t)b * NPOINT + qq) * 3;
        const size_t pb = ((size_t)b * N + id) * 3;
        const size_t ob = bbase + (size_t)qq * NSAMPLE + (t & 31);
        {
#pragma clang fp contract(off)
            out[ob + 0 * plane] = xyz[pb + 0] - new_xyz[cb + 0];
            out[ob + 1 * plane] = xyz[pb + 1] - new_xyz[cb + 1];
            out[ob + 2 * plane] = xyz[pb + 2] - new_xyz[cb + 2];
        }
    }
    __syncthreads();

    // Phase 2: wave w writes channel c = it*4+w; lanes 0-31 -> q0 row, 32-63 -> q1 row.
    const int l = t & 63;
    const int w = t >> 6;
    const int qq = (l < 32) ? q0 : q1;
    const size_t rowbase = bbase + (size_t)qq * NSAMPLE + (l & 31);
#pragma unroll
    for (int it = 0; it < 16; ++it) {
        const int c = it * 4 + w;
        out[rowbase + (size_t)(3 + c) * plane] = sf[l * 65 + c];
    }
}

// ---------------- ws-too-small fallbacks ----------------
__global__ void __launch_bounds__(256) ball_query_kernel(
    const float* __restrict__ xyz, const float* __restrict__ new_xyz,
    int* __restrict__ idx_out)
{
    const int wave = (blockIdx.x * blockDim.x + threadIdx.x) >> 6;
    const int lane = threadIdx.x & 63;
    if (wave >= B * NPOINT) return;
    const int b = wave / NPOINT;
    const float cx = new_xyz[(size_t)wave * 3 + 0];
    const float cy = new_xyz[(size_t)wave * 3 + 1];
    const float cz = new_xyz[(size_t)wave * 3 + 2];
    const unsigned long long lanemask_lt = (lane == 63) ? 0x7FFFFFFFFFFFFFFFull
                                                        : ((1ull << lane) - 1ull);
    linear_ball_fallback(xyz + (size_t)b * N * 3, cx, cy, cz, lane, lanemask_lt,
                         idx_out + (size_t)wave * NSAMPLE);
}

__global__ void __launch_bounds__(256) group_kernel(
    const float* __restrict__ xyz, const float* __restrict__ new_xyz,
    const float* __restrict__ feat, const int* __restrict__ idx_arr,
    float* __restrict__ out) {
    const int t = threadIdx.x;
    const int s = t & 31;
    const int jl = t >> 5;
    const int j = blockIdx.x * 8 + jl;
    const int b = blockIdx.y;

    const int id = idx_arr[((size_t)b * NPOINT + j) * NSAMPLE + s];

    const float px = xyz[((size_t)b * N + id) * 3 + 0] - new_xyz[((size_t)b * NPOINT + j) * 3 + 0];
    const float py = xyz[((size_t)b * N + id) * 3 + 1] - new_xyz[((size_t)b * NPOINT + j) * 3 + 1];
    const float pz = xyz[((size_t)b * N + id) * 3 + 2] - new_xyz[((size_t)b * NPOINT + j) * 3 + 2];

    const size_t plane = (size_t)NPOINT * NSAMPLE;
    const size_t obase = (size_t)b * (3 + C) * plane + (size_t)j * NSAMPLE + s;

    out[obase + 0 * plane] = px;
    out[obase + 1 * plane] = py;
    out[obase + 2 * plane] = pz;

    const float* __restrict__ fb = feat + (size_t)b * C * N;
#pragma unroll 8
    for (int c = 0; c < C; ++c) {
        out[obase + (size_t)(3 + c) * plane] = fb[(size_t)c * N + id];
    }
}

extern "C" void kernel_launch(void* const* d_in, const int* in_sizes, int n_in,
                              void* d_out, int out_size, void* d_ws, size_t ws_size,
                              hipStream_t stream) {
    const float* xyz     = (const float*)d_in[0];  // (B, N, 3)
    const float* new_xyz = (const float*)d_in[1];  // (B, NPOINT, 3)
    const float* feat    = (const float*)d_in[2];  // (B, C, N)
    float* out = (float*)d_out;

    // Workspace layout (contiguous)
    const size_t idx_bytes    = (size_t)B * NPOINT * NSAMPLE * sizeof(int);  // 1,048,576
    const size_t ft_bytes     = (size_t)B * N * C * sizeof(float);           // 8,388,608
    const size_t binned_bytes = (size_t)B * N * sizeof(float4);              //   524,288
    const size_t off_bytes    = (size_t)B * OFF_STRIDE * sizeof(int);        //     8,448
    const size_t cellw_bytes  = (size_t)B * CELLW_STRIDE * sizeof(int);      //     8,192
    const size_t qwork_bytes  = (size_t)B * CELLW_STRIDE * sizeof(int);      //     8,192
    const size_t qperm_bytes  = (size_t)B * NPOINT * sizeof(int);            //    32,768

    char* ws = (char*)d_ws;
    size_t o = 0;
    int*    idx_ws   = (int*)(ws + o);    o += idx_bytes;
    float*  ft       = (float*)(ws + o);  o += ft_bytes;
    float4* binned   = (float4*)(ws + o); o += binned_bytes;
    int*    off      = (int*)(ws + o);    o += off_bytes;
    int*    cellwork = (int*)(ws + o);    o += cellw_bytes;   // cellwork+qwork adjacent
    int*    qwork    = (int*)(ws + o);    o += qwork_bytes;
    int*    qperm    = (int*)(ws + o);    o += qperm_bytes;

    const bool use_grid = (ws_size >= o);

    if (use_grid) {
        // init counters (graph-safe async memset; covers cellwork+qwork, adjacent)
        hipMemsetAsync(cellwork, 0, cellw_bytes + qwork_bytes, stream);
        grid_hist_kernel<<<(B * (N + NPOINT) + 255) / 256, 256, 0, stream>>>(
            xyz, new_xyz, cellwork, qwork);
        grid_scan_kernel<<<2 * B, 1024, 0, stream>>>(cellwork, qwork, off);
        grid_scatter_kernel<<<(B * (N + NPOINT) + 255) / 256, 256, 0, stream>>>(
            xyz, new_xyz, cellwork, qwork, binned, qperm);
        ball_and_transpose_kernel<<<BALL_BLOCKS + TRANS_BLOCKS, 256, 0, stream>>>(
            binned, off, new_xyz, xyz, qperm, idx_ws, feat, ft);
        group2_kernel<<<B * NPOINT / 2, 256, 0, stream>>>(
            xyz, new_xyz, ft, idx_ws, qperm, out);
    } else {
        ball_query_kernel<<<(B * NPOINT) / 4, 256, 0, stream>>>(xyz, new_xyz, idx_ws);
        dim3 grid2(NPOINT / 8, B);
        group_kernel<<<grid2, 256, 0, stream>>>(xyz, new_xyz, feat, idx_ws, out);
    }
}

// Round 13
// 46.857 us; speedup vs baseline: 1.9255x; 1.1215x over previous
//
#include <hip/hip_runtime.h>

#define B 2
#define N 16384
#define NPOINT 4096
#define C 64
#define NSAMPLE 32

#define NCELL 1000        // 10x10x10 grid, cell size 0.1 == radius
#define CELLW_STRIDE 1024 // work array stride per batch
#define OFF_STRIDE 1056   // offsets stride per batch (1001 used)
#define CAP 192           // per-query candidate capacity (mean ~69)

#define HIST_BLOCKS ((B * (N + NPOINT) + 255) / 256)  // 160
#define TRANS_BLOCKS (B * (N / 64))                   // 512

// Threshold exactly as the JAX/numpy reference sees it:
// float32(double(0.1)*double(0.1)) = 0.009999999776482582f
__device__ __forceinline__ float r2_thresh() { return (float)(0.1 * 0.1); }

__device__ __forceinline__ int clamp09(int v) { return v < 0 ? 0 : (v > 9 ? 9 : v); }

__device__ __forceinline__ int cell_of(float x, float y, float z) {
    const int ix = clamp09((int)floorf(x * 10.0f));
    const int iy = clamp09((int)floorf(y * 10.0f));
    const int iz = clamp09((int)floorf(z * 10.0f));
    return (ix * 10 + iy) * 10 + iz;
}

// ---------------- Kernel H: histogram (blocks 0..159) ∥ transpose (160..671) ----------------
__global__ void __launch_bounds__(256) hist_transpose_kernel(
    const float* __restrict__ xyz, const float* __restrict__ new_xyz,
    int* __restrict__ cellwork, int* __restrict__ qwork,
    const float* __restrict__ feat, float* __restrict__ ft) {
    __shared__ float tile[64 * 65];
    const int t = threadIdx.x;

    if (blockIdx.x >= HIST_BLOCKS) {
        // ---- transpose branch ----
        const int tb = blockIdx.x - HIST_BLOCKS;    // 0..511
        const int b = tb / (N / 64);
        const int n0 = (tb % (N / 64)) * 64;
        const int l = t & 63;
        const int w = t >> 6;
#pragma unroll
        for (int it = 0; it < 16; ++it) {
            const int c = it * 4 + w;
            tile[c * 65 + l] = feat[((size_t)b * C + c) * N + n0 + l];
        }
        __syncthreads();
#pragma unroll
        for (int it = 0; it < 16; ++it) {
            const int nn = it * 4 + w;
            ft[((size_t)b * N + n0 + nn) * C + l] = tile[l * 65 + nn];
        }
        return;
    }

    const int i = blockIdx.x * blockDim.x + t;  // over B*(N+NPOINT)
    if (i < B * N) {
        const int b = i / N;
        const float x = xyz[(size_t)i * 3 + 0];
        const float y = xyz[(size_t)i * 3 + 1];
        const float z = xyz[(size_t)i * 3 + 2];
        atomicAdd(&cellwork[b * CELLW_STRIDE + cell_of(x, y, z)], 1);
    } else if (i < B * (N + NPOINT)) {
        const int qi = i - B * N;
        const int b = qi / NPOINT;
        const float x = new_xyz[(size_t)qi * 3 + 0];
        const float y = new_xyz[(size_t)qi * 3 + 1];
        const float z = new_xyz[(size_t)qi * 3 + 2];
        atomicAdd(&qwork[b * CELLW_STRIDE + cell_of(x, y, z)], 1);
    }
}

// ---------------- Kernel S: shuffle-based exclusive scan (2 barriers) ----------------
__global__ void __launch_bounds__(1024) grid_scan_kernel(
    int* __restrict__ cellwork, int* __restrict__ qwork, int* __restrict__ off) {
    __shared__ int wsum[16];
    const int blk = blockIdx.x;
    const int t = threadIdx.x;
    const int lane = t & 63;
    const int w = t >> 6;   // 16 waves
    int* __restrict__ arr = (blk < B) ? (cellwork + blk * CELLW_STRIDE)
                                      : (qwork + (blk - B) * CELLW_STRIDE);
    const int v = (t < NCELL) ? arr[t] : 0;

    int s = v;
#pragma unroll
    for (int d = 1; d < 64; d <<= 1) {
        const int u = __shfl_up(s, d, 64);
        if (lane >= d) s += u;
    }
    if (lane == 63) wsum[w] = s;
    __syncthreads();
    if (w == 0) {
        int p = (lane < 16) ? wsum[lane] : 0;
#pragma unroll
        for (int d = 1; d < 16; d <<= 1) {
            const int u = __shfl_up(p, d, 64);
            if (lane >= d) p += u;
        }
        if (lane < 16) wsum[lane] = p;
    }
    __syncthreads();
    const int prefix = (w > 0) ? wsum[w - 1] : 0;
    const int excl = s + prefix - v;
    if (blk < B && t <= NCELL) off[blk * OFF_STRIDE + t] = excl;  // off[1000] = N
    if (t < NCELL) arr[t] = excl;  // cursors for scatter
}

// ---------------- Kernel C: scatter points + queries ----------------
__global__ void __launch_bounds__(256) grid_scatter_kernel(
    const float* __restrict__ xyz, const float* __restrict__ new_xyz,
    int* __restrict__ cellwork, int* __restrict__ qwork,
    float4* __restrict__ binned, int* __restrict__ qperm) {
    const int i = blockIdx.x * blockDim.x + threadIdx.x;
    if (i < B * N) {
        const int b = i / N;
        const int p = i - b * N;
        const float x = xyz[(size_t)i * 3 + 0];
        const float y = xyz[(size_t)i * 3 + 1];
        const float z = xyz[(size_t)i * 3 + 2];
        const int c = cell_of(x, y, z);
        const int pos = atomicAdd(&cellwork[b * CELLW_STRIDE + c], 1);
        float4 v;
        v.x = x; v.y = y; v.z = z; v.w = __int_as_float(p);
        binned[(size_t)b * N + pos] = v;
    } else if (i < B * (N + NPOINT)) {
        const int qi = i - B * N;
        const int b = qi / NPOINT;
        const int j = qi - b * NPOINT;
        const float x = new_xyz[(size_t)qi * 3 + 0];
        const float y = new_xyz[(size_t)qi * 3 + 1];
        const float z = new_xyz[(size_t)qi * 3 + 2];
        const int c = cell_of(x, y, z);
        const int pos = atomicAdd(&qwork[b * CELLW_STRIDE + c], 1);
        qperm[b * NPOINT + pos] = j;
    }
}

// ---------------- exact linear-scan fallback (in-wave); out may be LDS or global ----------------
__device__ void linear_ball_fallback(const float* __restrict__ xb,
                                     float cx, float cy, float cz,
                                     int lane, unsigned long long lanemask_lt,
                                     int* out) {
    const float r2 = r2_thresh();
    int cnt = 0, first_idx = 0;
    for (int base = 0; base < N; base += 64) {
        const int i = base + lane;
        const float x = xb[i * 3 + 0];
        const float y = xb[i * 3 + 1];
        const float z = xb[i * 3 + 2];
        float d2;
        {
#pragma clang fp contract(off)
            float dx = x - cx;
            float dy = y - cy;
            float dz = z - cz;
            d2 = dx * dx + dy * dy + dz * dz;
        }
        const bool in = d2 < r2;
        const unsigned long long m = __ballot(in);
        if (in) {
            const int pos = cnt + __popcll(m & lanemask_lt);
            if (pos < NSAMPLE) out[pos] = i;
        }
        if (cnt == 0 && m != 0ull) first_idx = base + __builtin_ctzll(m);
        cnt += __popcll(m);
        if (cnt >= NSAMPLE) break;
    }
    if (cnt < NSAMPLE) {
        if (cnt == 0) first_idx = 0;
        for (int pos = cnt + lane; pos < NSAMPLE; pos += 64) out[pos] = first_idx;
    }
}

// Rank-select the NSAMPLE smallest indices from cand[0..K) (K <= CAP) -> out.
__device__ __forceinline__ void rank_select(const int* cand, int K, int lane,
                                            int* out) {
    const int e0 = (lane < K) ? cand[lane] : 0x7FFFFFFF;
    const int e1 = (64 + lane < K) ? cand[64 + lane] : 0x7FFFFFFF;
    const int e2 = (128 + lane < K) ? cand[128 + lane] : 0x7FFFFFFF;
    int r0 = 0, r1 = 0, r2i = 0;
    if (K <= 64) {
        for (int k = 0; k < K; ++k) { const int v = cand[k]; r0 += (v < e0); }
    } else if (K <= 128) {
        for (int k = 0; k < K; ++k) { const int v = cand[k]; r0 += (v < e0); r1 += (v < e1); }
    } else {
        for (int k = 0; k < K; ++k) {
            const int v = cand[k];
            r0 += (v < e0); r1 += (v < e1); r2i += (v < e2);
        }
    }
    if (lane < K && r0 < NSAMPLE) out[r0] = e0;
    if (64 + lane < K && r1 < NSAMPLE) out[r1] = e1;
    if (128 + lane < K && r2i < NSAMPLE) out[r2i] = e2;

    if (K < NSAMPLE) {
        int mn = min(e0, min(e1, e2));
#pragma unroll
        for (int d = 32; d; d >>= 1) mn = min(mn, __shfl_xor(mn, d));
        const int fill = (K > 0) ? mn : 0;
        for (int pos = K + lane; pos < NSAMPLE; pos += 64) out[pos] = fill;
    }
}

// Scan one window against one center; append in-ball ids to cand; returns K.
__device__ __forceinline__ int scan_window(
    const float4* __restrict__ bb, const int* __restrict__ ob,
    int lox, int hix, int loy, int hiy, int loz, int hiz,
    float cx, float cy, float cz, int lane,
    unsigned long long lanemask_lt, int* cand)
{
    const float r2 = r2_thresh();
    int K = 0;
    for (int ix = lox; ix <= hix; ++ix) {
        for (int iy = loy; iy <= hiy; ++iy) {
            const int rowc = (ix * 10 + iy) * 10;
            const int s0 = ob[rowc + loz];
            const int s1 = ob[rowc + hiz + 1];  // z cells contiguous -> one segment
            for (int cur = s0; cur < s1; cur += 64) {
                const int i = cur + lane;
                const bool valid = (i < s1);
                float4 pv;
                if (valid) pv = bb[i];
                else { pv.x = 1e9f; pv.y = 1e9f; pv.z = 1e9f; pv.w = 0.0f; }
                float d2;
                {
#pragma clang fp contract(off)
                    float dx = pv.x - cx, dy = pv.y - cy, dz = pv.z - cz;
                    d2 = dx * dx + dy * dy + dz * dz;
                }
                const bool in = valid && (d2 < r2);
                const unsigned long long m = __ballot(in);
                if (in) {
                    const int pos = K + __popcll(m & lanemask_lt);
                    if (pos < CAP) cand[pos] = __float_as_int(pv.w);
                }
                K += __popcll(m);
            }
        }
    }
    return K;
}

// ---------------- Kernel F: fused ball query + grouping ----------------
// 256 threads = 4 waves = 4 consecutive sorted queries. Ball query into LDS;
// group phase in TWO passes of 64 pairs reusing one sf buffer, keeping LDS at
// 20,240 B -> 8 blocks/CU = 32 waves/CU (round-9 fusion at full occupancy).
__global__ void __launch_bounds__(256) fused_kernel(
    const float4* __restrict__ binned,   // (B, N)
    const int* __restrict__ off,         // (B, OFF_STRIDE)
    const float* __restrict__ new_xyz,   // (B, NPOINT, 3)
    const float* __restrict__ xyz,       // (B, N, 3)
    const float* __restrict__ ft,        // (B, N, C)
    const int* __restrict__ qperm,       // (B, NPOINT)
    float* __restrict__ out)             // (B, 3+C, NPOINT, NSAMPLE)
{
    __shared__ int cand_s[4][CAP];      // 3072 B
    __shared__ int sidx[4 * NSAMPLE];   // 512 B
    __shared__ int sj[4];               // 16 B
    __shared__ float sf[64 * 65];       // 16640 B   (total 20240 B)

    const int t = threadIdx.x;
    const int lane = t & 63;
    const int w = t >> 6;   // wave = local query

    const int nwg = B * NPOINT / 4;                 // 2048, % 8 == 0
    const int g = blockIdx.x;
    const int swz = (g & 7) * (nwg / 8) + (g >> 3); // bijective XCD swizzle
    const int b = swz / (NPOINT / 4);
    const int p4 = swz % (NPOINT / 4);

    const int j = qperm[b * NPOINT + p4 * 4 + w];   // original query (broadcast)
    if (lane == 0) sj[w] = j;

    const float cx = new_xyz[((size_t)b * NPOINT + j) * 3 + 0];
    const float cy = new_xyz[((size_t)b * NPOINT + j) * 3 + 1];
    const float cz = new_xyz[((size_t)b * NPOINT + j) * 3 + 2];

    int* cand = cand_s[w];
    int* sout = sidx + w * NSAMPLE;
    const float4* __restrict__ bb = binned + (size_t)b * N;
    const int* __restrict__ ob = off + b * OFF_STRIDE;

    const unsigned long long lanemask_lt = (lane == 63) ? 0x7FFFFFFFFFFFFFFFull
                                                        : ((1ull << lane) - 1ull);

    const int lox = max(0, (int)floorf((cx - 0.1001f) * 10.0f));
    const int hix = min(9, (int)floorf((cx + 0.1001f) * 10.0f));
    const int loy = max(0, (int)floorf((cy - 0.1001f) * 10.0f));
    const int hiy = min(9, (int)floorf((cy + 0.1001f) * 10.0f));
    const int loz = max(0, (int)floorf((cz - 0.1001f) * 10.0f));
    const int hiz = min(9, (int)floorf((cz + 0.1001f) * 10.0f));

    const int K = scan_window(bb, ob, lox, hix, loy, hiy, loz, hiz,
                              cx, cy, cz, lane, lanemask_lt, cand);

    if (K > CAP) {  // pathological density: exact linear rescan (wave-uniform)
        linear_ball_fallback(xyz + (size_t)b * N * 3, cx, cy, cz, lane, lanemask_lt, sout);
    } else {
        rank_select(cand, K, lane, sout);
    }
    __syncthreads();

    const size_t plane = (size_t)NPOINT * NSAMPLE;
    const size_t bbase = (size_t)b * (3 + C) * plane;

    // xyz part: threads 0..127 -> one (query,slot) pair each (direct global)
    if (t < 128) {
        const int id = sidx[t];
        const int jq = sj[t >> 5];
        const int s = t & 31;
        const size_t cb = ((size_t)b * NPOINT + jq) * 3;
        const size_t pb = ((size_t)b * N + id) * 3;
        const size_t obx = bbase + (size_t)jq * NSAMPLE + s;
        {
#pragma clang fp contract(off)
            out[obx + 0 * plane] = xyz[pb + 0] - new_xyz[cb + 0];
            out[obx + 1 * plane] = xyz[pb + 1] - new_xyz[cb + 1];
            out[obx + 2 * plane] = xyz[pb + 2] - new_xyz[cb + 2];
        }
    }

    // group phase: two passes of 64 pairs (queries 2h, 2h+1), sf reused
#pragma unroll
    for (int h = 0; h < 2; ++h) {
        const int* sidxL = sidx + h * 64;
        // gather: 64 pairs x 16 lanes, one float4 each, 4 iterations
        {
            const int lane16 = t & 15;
            const int pg = t >> 4;  // 0..15
#pragma unroll
            for (int it = 0; it < 4; ++it) {
                const int pp = it * 16 + pg;
                const int id = sidxL[pp];
                const float4 v = *(const float4*)(ft + ((size_t)b * N + id) * C + lane16 * 4);
                float* dst = sf + pp * 65 + lane16 * 4;
                dst[0] = v.x; dst[1] = v.y; dst[2] = v.z; dst[3] = v.w;
            }
        }
        __syncthreads();
        // store: wave w owns channels c = it*4 + w; lanes 0-31 -> q(2h), 32-63 -> q(2h+1)
        const int q = sj[2 * h + (lane >> 5)];
        const size_t rowbase = bbase + (size_t)q * NSAMPLE + (lane & 31);
#pragma unroll
        for (int it = 0; it < 16; ++it) {
            const int c = it * 4 + w;
            out[rowbase + (size_t)(3 + c) * plane] = sf[lane * 65 + c];
        }
        __syncthreads();  // before sf reuse in next pass
    }
}

// ---------------- ws-too-small fallbacks (linear ball + direct group) ----------------
__global__ void __launch_bounds__(256) ball_query_kernel(
    const float* __restrict__ xyz, const float* __restrict__ new_xyz,
    int* __restrict__ idx_out)
{
    const int wave = (blockIdx.x * blockDim.x + threadIdx.x) >> 6;
    const int lane = threadIdx.x & 63;
    if (wave >= B * NPOINT) return;
    const int b = wave / NPOINT;
    const float cx = new_xyz[(size_t)wave * 3 + 0];
    const float cy = new_xyz[(size_t)wave * 3 + 1];
    const float cz = new_xyz[(size_t)wave * 3 + 2];
    const unsigned long long lanemask_lt = (lane == 63) ? 0x7FFFFFFFFFFFFFFFull
                                                        : ((1ull << lane) - 1ull);
    linear_ball_fallback(xyz + (size_t)b * N * 3, cx, cy, cz, lane, lanemask_lt,
                         idx_out + (size_t)wave * NSAMPLE);
}

__global__ void __launch_bounds__(256) group_kernel(
    const float* __restrict__ xyz, const float* __restrict__ new_xyz,
    const float* __restrict__ feat, const int* __restrict__ idx_arr,
    float* __restrict__ out) {
    const int t = threadIdx.x;
    const int s = t & 31;
    const int jl = t >> 5;
    const int j = blockIdx.x * 8 + jl;
    const int b = blockIdx.y;

    const int id = idx_arr[((size_t)b * NPOINT + j) * NSAMPLE + s];

    const float px = xyz[((size_t)b * N + id) * 3 + 0] - new_xyz[((size_t)b * NPOINT + j) * 3 + 0];
    const float py = xyz[((size_t)b * N + id) * 3 + 1] - new_xyz[((size_t)b * NPOINT + j) * 3 + 1];
    const float pz = xyz[((size_t)b * N + id) * 3 + 2] - new_xyz[((size_t)b * NPOINT + j) * 3 + 2];

    const size_t plane = (size_t)NPOINT * NSAMPLE;
    const size_t obase = (size_t)b * (3 + C) * plane + (size_t)j * NSAMPLE + s;

    out[obase + 0 * plane] = px;
    out[obase + 1 * plane] = py;
    out[obase + 2 * plane] = pz;

    const float* __restrict__ fb = feat + (size_t)b * C * N;
#pragma unroll 8
    for (int c = 0; c < C; ++c) {
        out[obase + (size_t)(3 + c) * plane] = fb[(size_t)c * N + id];
    }
}

extern "C" void kernel_launch(void* const* d_in, const int* in_sizes, int n_in,
                              void* d_out, int out_size, void* d_ws, size_t ws_size,
                              hipStream_t stream) {
    const float* xyz     = (const float*)d_in[0];  // (B, N, 3)
    const float* new_xyz = (const float*)d_in[1];  // (B, NPOINT, 3)
    const float* feat    = (const float*)d_in[2];  // (B, C, N)
    float* out = (float*)d_out;

    // Workspace layout (contiguous)
    const size_t idx_bytes    = (size_t)B * NPOINT * NSAMPLE * sizeof(int);  // fallback only
    const size_t ft_bytes     = (size_t)B * N * C * sizeof(float);           // 8,388,608
    const size_t binned_bytes = (size_t)B * N * sizeof(float4);              //   524,288
    const size_t off_bytes    = (size_t)B * OFF_STRIDE * sizeof(int);        //     8,448
    const size_t cellw_bytes  = (size_t)B * CELLW_STRIDE * sizeof(int);      //     8,192
    const size_t qwork_bytes  = (size_t)B * CELLW_STRIDE * sizeof(int);      //     8,192
    const size_t qperm_bytes  = (size_t)B * NPOINT * sizeof(int);            //    32,768

    char* ws = (char*)d_ws;
    size_t o = 0;
    int*    idx_ws   = (int*)(ws + o);    o += idx_bytes;
    float*  ft       = (float*)(ws + o);  o += ft_bytes;
    float4* binned   = (float4*)(ws + o); o += binned_bytes;
    int*    off      = (int*)(ws + o);    o += off_bytes;
    int*    cellwork = (int*)(ws + o);    o += cellw_bytes;   // cellwork+qwork adjacent
    int*    qwork    = (int*)(ws + o);    o += qwork_bytes;
    int*    qperm    = (int*)(ws + o);    o += qperm_bytes;

    const bool use_grid = (ws_size >= o);

    if (use_grid) {
        hipMemsetAsync(cellwork, 0, cellw_bytes + qwork_bytes, stream);
        hist_transpose_kernel<<<HIST_BLOCKS + TRANS_BLOCKS, 256, 0, stream>>>(
            xyz, new_xyz, cellwork, qwork, feat, ft);
        grid_scan_kernel<<<2 * B, 1024, 0, stream>>>(cellwork, qwork, off);
        grid_scatter_kernel<<<(B * (N + NPOINT) + 255) / 256, 256, 0, stream>>>(
            xyz, new_xyz, cellwork, qwork, binned, qperm);
        fused_kernel<<<B * NPOINT / 4, 256, 0, stream>>>(
            binned, off, new_xyz, xyz, ft, qperm, out);
    } else {
        ball_query_kernel<<<(B * NPOINT) / 4, 256, 0, stream>>>(xyz, new_xyz, idx_ws);
        dim3 grid2(NPOINT / 8, B);
        group_kernel<<<grid2, 256, 0, stream>>>(xyz, new_xyz, feat, idx_ws, out);
    }
}